// Round 3
// baseline (320.289 us; speedup 1.0000x reference)
//
#include <hip/hip_runtime.h>
#include <stdint.h>

typedef __attribute__((ext_vector_type(4))) float f32x4;
typedef __attribute__((ext_vector_type(8))) short bf16x8;

static __device__ __forceinline__ unsigned short f2bf(float x) {
  unsigned int u = __builtin_bit_cast(unsigned int, x);
  u = (u + 0x7fffu + ((u >> 16) & 1u)) >> 16;
  return (unsigned short)u;
}

#define GLD16(g, l)                                                            \
  __builtin_amdgcn_global_load_lds(                                            \
      (__attribute__((address_space(1))) const void*)(g),                      \
      (__attribute__((address_space(3))) void*)(l), 16, 0, 0)

// ---- pass1: dinv = rsqrt(rowsum(graph)); gb = bf16(dinv[row] * graph) ------
__global__ __launch_bounds__(256) void rowscale_cvt_k(
    const float* __restrict__ g, float* __restrict__ dinv,
    unsigned short* __restrict__ gb) {
  int row = blockIdx.x * 4 + (threadIdx.x >> 6);
  int lane = threadIdx.x & 63;
  const float* p = g + (long)row * 2048;
  float4 v[8];
  float s = 0.f;
#pragma unroll
  for (int i = 0; i < 8; ++i) {
    v[i] = *(const float4*)(p + (lane + i * 64) * 4);
    s += v[i].x + v[i].y + v[i].z + v[i].w;
  }
#pragma unroll
  for (int off = 32; off; off >>= 1) s += __shfl_xor(s, off, 64);
  float di = rsqrtf(s);
  if (lane == 0) dinv[row] = di;
  unsigned short* q = gb + (long)row * 2048;
#pragma unroll
  for (int i = 0; i < 8; ++i) {
    ushort4 u;
    u.x = f2bf(v[i].x * di); u.y = f2bf(v[i].y * di);
    u.z = f2bf(v[i].z * di); u.w = f2bf(v[i].w * di);
    *(ushort4*)(q + (lane + i * 64) * 4) = u;
  }
}

// ---- weights f32 -> bf16 ---------------------------------------------------
__global__ __launch_bounds__(256) void cvt_w_k(const float* __restrict__ W1,
                                               const float* __restrict__ W2,
                                               const float* __restrict__ Wout,
                                               unsigned short* __restrict__ wb) {
  int idx = blockIdx.x * 256 + threadIdx.x;  // 262144 total
  float v;
  if (idx < 65536) v = W1[idx];
  else if (idx < 131072) v = W2[idx - 65536];
  else v = Wout[idx - 131072];
  wb[idx] = f2bf(v);
}

// ---- node prep: agg[:, :256] = bf16(node); nodeT = (dinv*node)^T -----------
__global__ __launch_bounds__(256) void prep_node_k(
    const float* __restrict__ node, const float* __restrict__ dinv,
    unsigned short* __restrict__ nodeT, unsigned short* __restrict__ agg) {
  __shared__ unsigned short t[64 * 68];
  int tid = threadIdx.x;
  int m0 = blockIdx.x * 64, h0 = blockIdx.y * 64;
  long b = blockIdx.z;
#pragma unroll
  for (int i = 0; i < 4; ++i) {
    int idx = tid + 256 * i;
    int r = idx >> 4, c4 = idx & 15;
    long m = m0 + r;
    float4 v = *(const float4*)(node + (b * 2048 + m) * 256 + h0 + c4 * 4);
    float di = dinv[b * 2048 + m];
    ushort4 u;
    u.x = f2bf(v.x); u.y = f2bf(v.y); u.z = f2bf(v.z); u.w = f2bf(v.w);
    *(ushort4*)(agg + (b * 2048 + m) * 512 + h0 + c4 * 4) = u;
    t[(c4 * 4 + 0) * 68 + r] = f2bf(v.x * di);
    t[(c4 * 4 + 1) * 68 + r] = f2bf(v.y * di);
    t[(c4 * 4 + 2) * 68 + r] = f2bf(v.z * di);
    t[(c4 * 4 + 3) * 68 + r] = f2bf(v.w * di);
  }
  __syncthreads();
#pragma unroll
  for (int i = 0; i < 4; ++i) {
    int idx = tid + 256 * i;
    int hr = idx >> 4, c4 = idx & 15;
    ushort4 o = *(const ushort4*)(&t[hr * 68 + c4 * 4]);
    *(ushort4*)(nodeT + (b * 256 + h0 + hr) * 2048 + m0 + c4 * 4) = o;
  }
}

// ---- GEMM: C[128,256] per block = A[128,K] @ Bt[256,K]^T -------------------
// 8 waves (512 thr), wave tile 64x64 (2Mx4N). BK=64, double-buffered LDS 96KB.
// bf16 operands via global_load_lds w=16 with XOR-swizzled source (T2/m173).
template <bool BIAS, bool RELU, bool SCALE, bool TRANS, bool OUTF32>
__global__ __launch_bounds__(512, 1) void gemm128(
    const unsigned short* __restrict__ A, const unsigned short* __restrict__ Bt,
    const float* __restrict__ bias, const float* __restrict__ scale,
    void* __restrict__ Cp, int K, int lda, int ldbt, long bBatch, int ldc) {
  __shared__ char lds[98304];  // A: 2x16384 @0, B: 2x32768 @32768
  char* ldsA = lds;
  char* ldsB = lds + 32768;

  int tid = threadIdx.x;
  int lane = tid & 63;
  int w = tid >> 6;          // 0..7
  int wm = w >> 2, wn = w & 3;

  // XCD swizzle: 128 blocks -> 16 consecutive tiles (one batch) per XCD
  int bid = blockIdx.x;
  int tile = ((bid & 7) << 4) + (bid >> 3);
  long row0 = (long)tile * 128;
  int batch = (int)(row0 >> 11);
  const unsigned short* Bb = Bt + (long)batch * bBatch;

  int nt = K >> 6;
  f32x4 acc[4][4] = {};

  auto stageA = [&](int kt, int buf) {
#pragma unroll
    for (int i = 0; i < 2; ++i) {
      int slot = i * 512 + tid;
      int r = slot >> 3, j = slot & 7;
      int jg = j ^ (r & 7);
      GLD16(A + (row0 + r) * lda + kt * 64 + jg * 8,
            ldsA + buf * 16384 + (i * 8 + w) * 1024);
    }
  };
  auto stageB = [&](int kt, int buf) {
#pragma unroll
    for (int i = 0; i < 4; ++i) {
      int slot = i * 512 + tid;
      int c = slot >> 3, j = slot & 7;
      int jg = j ^ (c & 7);
      GLD16(Bb + (long)c * ldbt + kt * 64 + jg * 8,
            ldsB + buf * 32768 + (i * 8 + w) * 1024);
    }
  };
  auto compute = [&](int buf) {
    char* bA = ldsA + buf * 16384;
    char* bB = ldsB + buf * 32768;
    bf16x8 a[4][2], bb[4][2];
#pragma unroll
    for (int m = 0; m < 4; ++m)
#pragma unroll
      for (int kk = 0; kk < 2; ++kk) {
        int row = wm * 64 + m * 16 + (lane & 15);
        int off = (row * 128 + kk * 64 + (lane >> 4) * 16) ^ ((row & 7) << 4);
        a[m][kk] = *(const bf16x8*)(bA + off);
      }
#pragma unroll
    for (int n = 0; n < 4; ++n)
#pragma unroll
      for (int kk = 0; kk < 2; ++kk) {
        int col = wn * 64 + n * 16 + (lane & 15);
        int off = (col * 128 + kk * 64 + (lane >> 4) * 16) ^ ((col & 7) << 4);
        bb[n][kk] = *(const bf16x8*)(bB + off);
      }
#pragma unroll
    for (int m = 0; m < 4; ++m)
#pragma unroll
      for (int n = 0; n < 4; ++n) {
        acc[m][n] = __builtin_amdgcn_mfma_f32_16x16x32_bf16(a[m][0], bb[n][0],
                                                            acc[m][n], 0, 0, 0);
        acc[m][n] = __builtin_amdgcn_mfma_f32_16x16x32_bf16(a[m][1], bb[n][1],
                                                            acc[m][n], 0, 0, 0);
      }
  };

  stageA(0, 0);
  stageB(0, 0);
  __syncthreads();

  int cur = 0;
  for (int t = 0; t < nt; ++t) {
    int nxt = cur ^ 1;
    if (t + 1 < nt) {
      stageA(t + 1, nxt);
      stageB(t + 1, nxt);
    }
    compute(cur);
    __syncthreads();
    cur = nxt;
  }

  // epilogue: C/D layout col=lane&15, row=(lane>>4)*4+r (m89-verified)
  if (TRANS) {
    unsigned short* tb = (unsigned short*)lds;  // [256 cols][136 pad]
#pragma unroll
    for (int m = 0; m < 4; ++m)
#pragma unroll
      for (int n = 0; n < 4; ++n) {
        int col = wn * 64 + n * 16 + (lane & 15);
        float bv = BIAS ? bias[col] : 0.f;
#pragma unroll
        for (int r = 0; r < 4; ++r) {
          int rl = wm * 64 + m * 16 + (lane >> 4) * 4 + r;
          float v = acc[m][n][r];
          if (BIAS) v += bv;
          if (RELU) v = fmaxf(v, 0.f);
          if (SCALE) v *= scale[row0 + rl];
          tb[col * 136 + rl] = f2bf(v);
        }
      }
    __syncthreads();
    unsigned short* C = (unsigned short*)Cp;
    int rin = (int)(row0 & 2047);
#pragma unroll
    for (int i = 0; i < 8; ++i) {
      int id = i * 512 + tid;      // 4096 chunks of 8 bf16
      int col = id >> 4, seg = id & 15;
      bf16x8 u = *(const bf16x8*)(tb + col * 136 + seg * 8);
      *(bf16x8*)(C + ((long)batch * 256 + col) * 2048 + rin + seg * 8) = u;
    }
  } else {
#pragma unroll
    for (int m = 0; m < 4; ++m)
#pragma unroll
      for (int n = 0; n < 4; ++n) {
        int col = wn * 64 + n * 16 + (lane & 15);
        float bv = BIAS ? bias[col] : 0.f;
#pragma unroll
        for (int r = 0; r < 4; ++r) {
          long row = row0 + wm * 64 + m * 16 + (lane >> 4) * 4 + r;
          float v = acc[m][n][r];
          if (BIAS) v += bv;
          if (RELU) v = fmaxf(v, 0.f);
          if (SCALE) v *= scale[row];
          if (OUTF32) ((float*)Cp)[row * ldc + col] = v;
          else ((unsigned short*)Cp)[row * ldc + col] = f2bf(v);
        }
      }
  }
}

extern "C" void kernel_launch(void* const* d_in, const int* in_sizes, int n_in,
                              void* d_out, int out_size, void* d_ws,
                              size_t ws_size, hipStream_t stream) {
  const float* node = (const float*)d_in[0];   // [8,2048,256]
  const float* graph = (const float*)d_in[1];  // [8,2048,2048]
  const float* W1 = (const float*)d_in[2];
  const float* b1 = (const float*)d_in[3];
  const float* W2 = (const float*)d_in[4];
  const float* b2 = (const float*)d_in[5];
  const float* Wout = (const float*)d_in[6];   // [256,512]
  const float* bout = (const float*)d_in[7];
  float* out = (float*)d_out;

  char* p = (char*)d_ws;
  float* dinv = (float*)p;                    p += 16384 * 4;
  unsigned short* wb = (unsigned short*)p;    p += 262144 * 2;
  unsigned short* gb = (unsigned short*)p;    p += 8L * 2048 * 2048 * 2;  // 64MB
  unsigned short* nodeT = (unsigned short*)p; p += 8L * 256 * 2048 * 2;  // /X1sT
  unsigned short* bufT = (unsigned short*)p;  p += 8L * 2048 * 256 * 2;  // A1/A2
  unsigned short* agg = (unsigned short*)p;   p += 8L * 2048 * 512 * 2;

  rowscale_cvt_k<<<4096, 256, 0, stream>>>(graph, dinv, gb);
  cvt_w_k<<<1024, 256, 0, stream>>>(W1, W2, Wout, wb);
  prep_node_k<<<dim3(32, 4, 8), 256, 0, stream>>>(node, dinv, nodeT, agg);

  // G1: A1 = gb @ nodeT^T
  gemm128<false, false, false, false, false><<<128, 512, 0, stream>>>(
      gb, nodeT, nullptr, nullptr, bufT, 2048, 2048, 2048, 256L * 2048, 256);
  // F1: X1s^T = (dinv .* relu(A1 @ W1^T + b1))^T -> nodeT
  gemm128<true, true, true, true, false><<<128, 512, 0, stream>>>(
      bufT, wb, b1, dinv, nodeT, 256, 256, 256, 0, 2048);
  // G2: A2 = gb @ X1s^T^T
  gemm128<false, false, false, false, false><<<128, 512, 0, stream>>>(
      gb, nodeT, nullptr, nullptr, bufT, 2048, 2048, 2048, 256L * 2048, 256);
  // F2: X2 = relu(A2 @ W2^T + b2) -> agg[:, 256:512]
  gemm128<true, true, false, false, false><<<128, 512, 0, stream>>>(
      bufT, wb + 65536, b2, nullptr, agg + 256, 256, 256, 256, 0, 512);
  // F3: out = relu(agg @ Wout^T + bout)  (K=512, f32 out)
  gemm128<true, true, false, false, true><<<128, 512, 0, stream>>>(
      agg, wb + 131072, bout, nullptr, out, 512, 512, 512, 0, 256);
}

// Round 4
// 309.970 us; speedup vs baseline: 1.0333x; 1.0333x over previous
//
#include <hip/hip_runtime.h>
#include <stdint.h>

typedef __attribute__((ext_vector_type(4))) float f32x4;
typedef __attribute__((ext_vector_type(8))) short bf16x8;

static __device__ __forceinline__ unsigned short f2bf(float x) {
  unsigned int u = __builtin_bit_cast(unsigned int, x);
  u = (u + 0x7fffu + ((u >> 16) & 1u)) >> 16;
  return (unsigned short)u;
}

#define GLD16(g, l)                                                            \
  __builtin_amdgcn_global_load_lds(                                            \
      (__attribute__((address_space(1))) const void*)(g),                      \
      (__attribute__((address_space(3))) void*)(l), 16, 0, 0)

// ---- pass1: dinv = rsqrt(rowsum(graph)); gb = bf16(dinv[row] * graph) ------
__global__ __launch_bounds__(256) void rowscale_cvt_k(
    const float* __restrict__ g, float* __restrict__ dinv,
    unsigned short* __restrict__ gb) {
  int row = blockIdx.x * 4 + (threadIdx.x >> 6);
  int lane = threadIdx.x & 63;
  const float* p = g + (long)row * 2048;
  float4 v[8];
  float s = 0.f;
#pragma unroll
  for (int i = 0; i < 8; ++i) {
    v[i] = *(const float4*)(p + (lane + i * 64) * 4);
    s += v[i].x + v[i].y + v[i].z + v[i].w;
  }
#pragma unroll
  for (int off = 32; off; off >>= 1) s += __shfl_xor(s, off, 64);
  float di = rsqrtf(s);
  if (lane == 0) dinv[row] = di;
  unsigned short* q = gb + (long)row * 2048;
#pragma unroll
  for (int i = 0; i < 8; ++i) {
    ushort4 u;
    u.x = f2bf(v[i].x * di); u.y = f2bf(v[i].y * di);
    u.z = f2bf(v[i].z * di); u.w = f2bf(v[i].w * di);
    *(ushort4*)(q + (lane + i * 64) * 4) = u;
  }
}

// ---- weights f32 -> bf16 ---------------------------------------------------
__global__ __launch_bounds__(256) void cvt_w_k(const float* __restrict__ W1,
                                               const float* __restrict__ W2,
                                               const float* __restrict__ Wout,
                                               unsigned short* __restrict__ wb) {
  int idx = blockIdx.x * 256 + threadIdx.x;  // 262144 total
  float v;
  if (idx < 65536) v = W1[idx];
  else if (idx < 131072) v = W2[idx - 65536];
  else v = Wout[idx - 131072];
  wb[idx] = f2bf(v);
}

// ---- node prep: agg[:, :256] = bf16(node); nodeT = (dinv*node)^T -----------
__global__ __launch_bounds__(256) void prep_node_k(
    const float* __restrict__ node, const float* __restrict__ dinv,
    unsigned short* __restrict__ nodeT, unsigned short* __restrict__ agg) {
  __shared__ unsigned short t[64 * 68];
  int tid = threadIdx.x;
  int m0 = blockIdx.x * 64, h0 = blockIdx.y * 64;
  long b = blockIdx.z;
#pragma unroll
  for (int i = 0; i < 4; ++i) {
    int idx = tid + 256 * i;
    int r = idx >> 4, c4 = idx & 15;
    long m = m0 + r;
    float4 v = *(const float4*)(node + (b * 2048 + m) * 256 + h0 + c4 * 4);
    float di = dinv[b * 2048 + m];
    ushort4 u;
    u.x = f2bf(v.x); u.y = f2bf(v.y); u.z = f2bf(v.z); u.w = f2bf(v.w);
    *(ushort4*)(agg + (b * 2048 + m) * 512 + h0 + c4 * 4) = u;
    t[(c4 * 4 + 0) * 68 + r] = f2bf(v.x * di);
    t[(c4 * 4 + 1) * 68 + r] = f2bf(v.y * di);
    t[(c4 * 4 + 2) * 68 + r] = f2bf(v.z * di);
    t[(c4 * 4 + 3) * 68 + r] = f2bf(v.w * di);
  }
  __syncthreads();
#pragma unroll
  for (int i = 0; i < 4; ++i) {
    int idx = tid + 256 * i;
    int hr = idx >> 4, c4 = idx & 15;
    ushort4 o = *(const ushort4*)(&t[hr * 68 + c4 * 4]);
    *(ushort4*)(nodeT + (b * 256 + h0 + hr) * 2048 + m0 + c4 * 4) = o;
  }
}

// ---- GEMM: C[128,128] per block = A[128,K] @ Bt[col0:+128, K]^T ------------
// m97 structure: 4 waves (each 64x64, a[4] x b[4] frags), BK=64, dbuf LDS 64KB
// -> 2 blocks/CU, grid 256 (full machine). global_load_lds w=16, XOR swizzle.
template <bool BIAS, bool RELU, bool SCALE, bool TRANS, bool OUTF32>
__global__ __launch_bounds__(256, 2) void gemm_t(
    const unsigned short* __restrict__ A, const unsigned short* __restrict__ Bt,
    const float* __restrict__ bias, const float* __restrict__ scale,
    void* __restrict__ Cp, int K, int lda, int ldbt, long bBatch, int ldc) {
  __shared__ char lds[65536];  // A: 2x16KB @0, B: 2x16KB @32768
  char* ldsA = lds;
  char* ldsB = lds + 32768;

  int tid = threadIdx.x;
  int lane = tid & 63;
  int w = tid >> 6;           // 0..3
  int wm = w >> 1, wn = w & 1;

  // 256 blocks: bid&7 = batch (-> one XCD per batch); 16 M-tiles x 2 N-tiles
  int bid = blockIdx.x;
  int gt = ((bid & 7) << 5) + (bid >> 3);  // 0..255
  int mt = gt >> 1;
  int col0 = (gt & 1) * 128;
  long row0 = (long)mt * 128;
  int batch = mt >> 4;
  const unsigned short* Bb = Bt + (long)batch * bBatch;

  int nt = K >> 6;
  f32x4 acc[4][4] = {};

  auto stageA = [&](int kt, int buf) {
#pragma unroll
    for (int i = 0; i < 4; ++i) {
      int slot = i * 256 + tid;  // 0..1023
      int r = slot >> 3, j = slot & 7;
      int jg = j ^ (r & 7);
      GLD16(A + (row0 + r) * (long)lda + kt * 64 + jg * 8,
            ldsA + buf * 16384 + (i * 4 + w) * 1024);
    }
  };
  auto stageB = [&](int kt, int buf) {
#pragma unroll
    for (int i = 0; i < 4; ++i) {
      int slot = i * 256 + tid;
      int c = slot >> 3, j = slot & 7;
      int jg = j ^ (c & 7);
      GLD16(Bb + (long)(col0 + c) * ldbt + kt * 64 + jg * 8,
            ldsB + buf * 16384 + (i * 4 + w) * 1024);
    }
  };
  auto compute = [&](int buf) {
    char* bA = ldsA + buf * 16384;
    char* bB = ldsB + buf * 16384;
    bf16x8 a[4][2], bb[4][2];
#pragma unroll
    for (int m = 0; m < 4; ++m)
#pragma unroll
      for (int kk = 0; kk < 2; ++kk) {
        int row = wm * 64 + m * 16 + (lane & 15);
        int off = (row * 128 + kk * 64 + (lane >> 4) * 16) ^ ((row & 7) << 4);
        a[m][kk] = *(const bf16x8*)(bA + off);
      }
#pragma unroll
    for (int n = 0; n < 4; ++n)
#pragma unroll
      for (int kk = 0; kk < 2; ++kk) {
        int col = wn * 64 + n * 16 + (lane & 15);
        int off = (col * 128 + kk * 64 + (lane >> 4) * 16) ^ ((col & 7) << 4);
        bb[n][kk] = *(const bf16x8*)(bB + off);
      }
#pragma unroll
    for (int m = 0; m < 4; ++m)
#pragma unroll
      for (int n = 0; n < 4; ++n) {
        acc[m][n] = __builtin_amdgcn_mfma_f32_16x16x32_bf16(a[m][0], bb[n][0],
                                                            acc[m][n], 0, 0, 0);
        acc[m][n] = __builtin_amdgcn_mfma_f32_16x16x32_bf16(a[m][1], bb[n][1],
                                                            acc[m][n], 0, 0, 0);
      }
  };

  stageA(0, 0);
  stageB(0, 0);
  __syncthreads();

  int cur = 0;
  for (int t = 0; t < nt; ++t) {
    int nxt = cur ^ 1;
    if (t + 1 < nt) {
      stageA(t + 1, nxt);
      stageB(t + 1, nxt);
    }
    compute(cur);
    __syncthreads();
    cur = nxt;
  }

  // epilogue: C/D layout col=lane&15, row=(lane>>4)*4+r (m89-verified)
  if (TRANS) {
    unsigned short* tb = (unsigned short*)lds;  // [128 local cols][136 pad]
#pragma unroll
    for (int m = 0; m < 4; ++m)
#pragma unroll
      for (int n = 0; n < 4; ++n) {
        int lc = wn * 64 + n * 16 + (lane & 15);
        float bv = BIAS ? bias[col0 + lc] : 0.f;
#pragma unroll
        for (int r = 0; r < 4; ++r) {
          int rl = wm * 64 + m * 16 + (lane >> 4) * 4 + r;
          float v = acc[m][n][r];
          if (BIAS) v += bv;
          if (RELU) v = fmaxf(v, 0.f);
          if (SCALE) v *= scale[row0 + rl];
          tb[lc * 136 + rl] = f2bf(v);
        }
      }
    __syncthreads();
    unsigned short* C = (unsigned short*)Cp;
    int rin = (int)(row0 & 2047);
#pragma unroll
    for (int i = 0; i < 8; ++i) {
      int id = i * 256 + tid;  // 2048 chunks of 8 bf16
      int lc = id >> 4, seg = id & 15;
      bf16x8 u = *(const bf16x8*)(tb + lc * 136 + seg * 8);
      *(bf16x8*)(C + ((long)batch * 256 + col0 + lc) * 2048 + rin + seg * 8) = u;
    }
  } else {
#pragma unroll
    for (int m = 0; m < 4; ++m)
#pragma unroll
      for (int n = 0; n < 4; ++n) {
        int col = col0 + wn * 64 + n * 16 + (lane & 15);
        float bv = BIAS ? bias[col] : 0.f;
#pragma unroll
        for (int r = 0; r < 4; ++r) {
          long row = row0 + wm * 64 + m * 16 + (lane >> 4) * 4 + r;
          float v = acc[m][n][r];
          if (BIAS) v += bv;
          if (RELU) v = fmaxf(v, 0.f);
          if (SCALE) v *= scale[row];
          if (OUTF32) ((float*)Cp)[row * ldc + col] = v;
          else ((unsigned short*)Cp)[row * ldc + col] = f2bf(v);
        }
      }
  }
}

extern "C" void kernel_launch(void* const* d_in, const int* in_sizes, int n_in,
                              void* d_out, int out_size, void* d_ws,
                              size_t ws_size, hipStream_t stream) {
  const float* node = (const float*)d_in[0];   // [8,2048,256]
  const float* graph = (const float*)d_in[1];  // [8,2048,2048]
  const float* W1 = (const float*)d_in[2];
  const float* b1 = (const float*)d_in[3];
  const float* W2 = (const float*)d_in[4];
  const float* b2 = (const float*)d_in[5];
  const float* Wout = (const float*)d_in[6];   // [256,512]
  const float* bout = (const float*)d_in[7];
  float* out = (float*)d_out;

  char* p = (char*)d_ws;
  float* dinv = (float*)p;                    p += 16384 * 4;
  unsigned short* wb = (unsigned short*)p;    p += 262144 * 2;
  unsigned short* gb = (unsigned short*)p;    p += 8L * 2048 * 2048 * 2;  // 64MB
  unsigned short* nodeT = (unsigned short*)p; p += 8L * 256 * 2048 * 2;  // /X1sT
  unsigned short* bufT = (unsigned short*)p;  p += 8L * 2048 * 256 * 2;  // A1/A2
  unsigned short* agg = (unsigned short*)p;   p += 8L * 2048 * 512 * 2;

  rowscale_cvt_k<<<4096, 256, 0, stream>>>(graph, dinv, gb);
  cvt_w_k<<<1024, 256, 0, stream>>>(W1, W2, Wout, wb);
  prep_node_k<<<dim3(32, 4, 8), 256, 0, stream>>>(node, dinv, nodeT, agg);

  // G1: A1 = gb @ nodeT^T
  gemm_t<false, false, false, false, false><<<256, 256, 0, stream>>>(
      gb, nodeT, nullptr, nullptr, bufT, 2048, 2048, 2048, 256L * 2048, 256);
  // F1: X1s^T = (dinv .* relu(A1 @ W1^T + b1))^T -> nodeT
  gemm_t<true, true, true, true, false><<<256, 256, 0, stream>>>(
      bufT, wb, b1, dinv, nodeT, 256, 256, 256, 0, 2048);
  // G2: A2 = gb @ X1s^T^T
  gemm_t<false, false, false, false, false><<<256, 256, 0, stream>>>(
      gb, nodeT, nullptr, nullptr, bufT, 2048, 2048, 2048, 256L * 2048, 256);
  // F2: X2 = relu(A2 @ W2^T + b2) -> agg[:, 256:512]
  gemm_t<true, true, false, false, false><<<256, 256, 0, stream>>>(
      bufT, wb + 65536, b2, nullptr, agg + 256, 256, 256, 256, 0, 512);
  // F3: out = relu(agg @ Wout^T + bout)  (K=512, f32 out)
  gemm_t<true, true, false, false, true><<<256, 256, 0, stream>>>(
      agg, wb + 131072, bout, nullptr, out, 512, 512, 512, 0, 256);
}